// Round 1
// baseline (107.786 us; speedup 1.0000x reference)
//
#include <hip/hip_runtime.h>
#include <hip/hip_bf16.h>

#define NN 4096      // N = 2*B
#define BB 2048      // B
#define DD 512       // D
#define TM 128       // C tile (M and N)
#define BK 64        // K tile

typedef __bf16 bf16x8 __attribute__((ext_vector_type(8)));
typedef float  f32x4  __attribute__((ext_vector_type(4)));

__device__ __forceinline__ unsigned short f2bf(float x) {
    unsigned int u = __float_as_uint(x);
    unsigned int r = (u + 0x7fffu + ((u >> 16) & 1u)) >> 16;  // RNE; inputs never NaN/Inf
    return (unsigned short)r;
}

// ---------------------------------------------------------------------------
// Kernel A: row-normalize z = [z_i; z_j], store bf16 zn[N][D] in workspace.
// One 64-lane wave per row, 4 rows per 256-thread block.
// ---------------------------------------------------------------------------
__global__ __launch_bounds__(256) void normalize_kernel(
        const float* __restrict__ z_i, const float* __restrict__ z_j,
        unsigned short* __restrict__ zn) {
    int row  = blockIdx.x * 4 + (threadIdx.x >> 6);
    int lane = threadIdx.x & 63;
    const float* src = (row < BB) ? (z_i + (size_t)row * DD)
                                  : (z_j + (size_t)(row - BB) * DD);
    const float4* s4 = (const float4*)src;
    float4 v0 = s4[lane * 2 + 0];
    float4 v1 = s4[lane * 2 + 1];
    float ss = v0.x*v0.x + v0.y*v0.y + v0.z*v0.z + v0.w*v0.w
             + v1.x*v1.x + v1.y*v1.y + v1.z*v1.z + v1.w*v1.w;
    #pragma unroll
    for (int off = 1; off < 64; off <<= 1) ss += __shfl_xor(ss, off, 64);
    float inv = 1.0f / fmaxf(sqrtf(ss), 1e-8f);

    float f[8] = {v0.x, v0.y, v0.z, v0.w, v1.x, v1.y, v1.z, v1.w};
    unsigned int p[4];
    #pragma unroll
    for (int k = 0; k < 4; ++k) {
        unsigned int lo = f2bf(f[2*k] * inv);
        unsigned int hi = f2bf(f[2*k+1] * inv);
        p[k] = lo | (hi << 16);
    }
    uint4 out = make_uint4(p[0], p[1], p[2], p[3]);
    *(uint4*)(zn + (size_t)row * DD + lane * 8) = out;
}

// ---------------------------------------------------------------------------
// Kernel B: sim = (zn @ zn^T) * 2, rowsum[i] += sum_j exp(sim[i][j]).
// 128x128 C-tile per 256-thread block (4 waves, 2x2 quadrants of 64x64).
// MFMA 16x16x32 bf16; LDS chunks XOR-swizzled (8-elt/16B granularity).
// ---------------------------------------------------------------------------
__global__ __launch_bounds__(256) void simexp_kernel(
        const unsigned short* __restrict__ zn, float* __restrict__ rowsum) {
    __shared__ __align__(16) unsigned short As[TM][BK];
    __shared__ __align__(16) unsigned short Bs[TM][BK];

    const int bi = blockIdx.y, bj = blockIdx.x;
    const int tid  = threadIdx.x;
    const int wave = tid >> 6, lane = tid & 63;
    const int wr = wave >> 1, wc = wave & 1;   // 2x2 wave grid, 64x64 each
    const int lrow = lane & 15, quad = lane >> 4;

    f32x4 acc[4][4];
    #pragma unroll
    for (int i = 0; i < 4; ++i)
        #pragma unroll
        for (int j = 0; j < 4; ++j) acc[i][j] = (f32x4){0.f, 0.f, 0.f, 0.f};

    const int c  = tid & 7;      // 16B chunk within BK
    const int r0 = tid >> 3;     // 0..31

    for (int kb = 0; kb < DD; kb += BK) {
        __syncthreads();
        #pragma unroll
        for (int rr = 0; rr < 4; ++rr) {
            int r  = r0 + rr * 32;
            int pc = c ^ (r & 7);  // XOR swizzle
            uint4 va = *(const uint4*)(zn + (size_t)(bi*TM + r) * DD + kb + c*8);
            uint4 vb = *(const uint4*)(zn + (size_t)(bj*TM + r) * DD + kb + c*8);
            *(uint4*)&As[r][pc * 8] = va;
            *(uint4*)&Bs[r][pc * 8] = vb;
        }
        __syncthreads();

        #pragma unroll
        for (int s = 0; s < 2; ++s) {           // two K=32 steps per BK=64
            bf16x8 a[4], b[4];
            #pragma unroll
            for (int ti = 0; ti < 4; ++ti) {
                int m = wr*64 + ti*16 + lrow;
                int p = (s*4 + quad) ^ (m & 7);
                a[ti] = *(const bf16x8*)&As[m][p * 8];
            }
            #pragma unroll
            for (int tj = 0; tj < 4; ++tj) {
                int n = wc*64 + tj*16 + lrow;
                int p = (s*4 + quad) ^ (n & 7);
                b[tj] = *(const bf16x8*)&Bs[n][p * 8];
            }
            #pragma unroll
            for (int ti = 0; ti < 4; ++ti)
                #pragma unroll
                for (int tj = 0; tj < 4; ++tj)
                    acc[ti][tj] = __builtin_amdgcn_mfma_f32_16x16x32_bf16(
                        a[ti], b[tj], acc[ti][tj], 0, 0, 0);
        }
    }

    // Epilogue: e = exp(2*cos); per-row sums.
    // C/D layout: col = lane&15, row = quad*4 + reg   (verified m89/m91)
    #pragma unroll
    for (int ti = 0; ti < 4; ++ti) {
        float rp[4] = {0.f, 0.f, 0.f, 0.f};
        #pragma unroll
        for (int tj = 0; tj < 4; ++tj)
            #pragma unroll
            for (int reg = 0; reg < 4; ++reg)
                rp[reg] += __expf(acc[ti][tj][reg] * 2.0f);
        #pragma unroll
        for (int off = 1; off < 16; off <<= 1)
            #pragma unroll
            for (int reg = 0; reg < 4; ++reg)
                rp[reg] += __shfl_xor(rp[reg], off, 64);
        if (lrow == 0) {
            int grow = bi*TM + wr*64 + ti*16 + quad*4;
            #pragma unroll
            for (int reg = 0; reg < 4; ++reg)
                atomicAdd(&rowsum[grow + reg], rp[reg]);
        }
    }
}

// ---------------------------------------------------------------------------
// Kernel C: rowloss[i] = log(rowsum[i] - exp(sim_ii)) - sim_{i,partner}
// One wave per row; fp32 dots over the same bf16 zn the GEMM consumed,
// so exp(sim_ii) cancels the GEMM's diagonal term product-exactly.
// ---------------------------------------------------------------------------
__global__ __launch_bounds__(256) void rowloss_kernel(
        const unsigned short* __restrict__ zn, const float* __restrict__ rowsum,
        float* __restrict__ rowloss) {
    int row  = blockIdx.x * 4 + (threadIdx.x >> 6);
    int lane = threadIdx.x & 63;
    int partner = (row < BB) ? row + BB : row - BB;

    bf16x8 a = *(const bf16x8*)(zn + (size_t)row * DD + lane * 8);
    bf16x8 p = *(const bf16x8*)(zn + (size_t)partner * DD + lane * 8);
    float self = 0.f, pos = 0.f;
    #pragma unroll
    for (int k = 0; k < 8; ++k) {
        float av = (float)a[k], pv = (float)p[k];
        self += av * av;
        pos  += av * pv;
    }
    #pragma unroll
    for (int off = 1; off < 64; off <<= 1) {
        self += __shfl_xor(self, off, 64);
        pos  += __shfl_xor(pos,  off, 64);
    }
    if (lane == 0)
        rowloss[row] = logf(rowsum[row] - __expf(2.0f * self)) - 2.0f * pos;
}

// ---------------------------------------------------------------------------
// Kernel D: final mean
// ---------------------------------------------------------------------------
__global__ __launch_bounds__(256) void final_kernel(
        const float* __restrict__ rowloss, float* __restrict__ out) {
    __shared__ float s[256];
    float v = 0.f;
    for (int i = threadIdx.x; i < NN; i += 256) v += rowloss[i];
    s[threadIdx.x] = v;
    __syncthreads();
    for (int off = 128; off > 0; off >>= 1) {
        if (threadIdx.x < off) s[threadIdx.x] += s[threadIdx.x + off];
        __syncthreads();
    }
    if (threadIdx.x == 0) out[0] = s[0] / (float)NN;
}

extern "C" void kernel_launch(void* const* d_in, const int* in_sizes, int n_in,
                              void* d_out, int out_size, void* d_ws, size_t ws_size,
                              hipStream_t stream) {
    const float* z_i = (const float*)d_in[0];
    const float* z_j = (const float*)d_in[1];
    float* out = (float*)d_out;

    unsigned short* zn = (unsigned short*)d_ws;                       // N*D bf16 = 4 MB
    float* rowsum  = (float*)((char*)d_ws + (size_t)NN * DD * 2);     // N floats
    float* rowloss = rowsum + NN;                                     // N floats

    hipMemsetAsync(rowsum, 0, NN * sizeof(float), stream);
    normalize_kernel<<<NN / 4, 256, 0, stream>>>(z_i, z_j, zn);
    simexp_kernel<<<dim3(NN / TM, NN / TM), 256, 0, stream>>>(zn, rowsum);
    rowloss_kernel<<<NN / 4, 256, 0, stream>>>(zn, rowsum, rowloss);
    final_kernel<<<1, 256, 0, stream>>>(rowloss, out);
}

// Round 2
// 106.603 us; speedup vs baseline: 1.0111x; 1.0111x over previous
//
#include <hip/hip_runtime.h>
#include <hip/hip_bf16.h>

#define NN 4096      // N = 2*B
#define BB 2048      // B
#define DD 512       // D
#define TM 128       // C tile (M and N)
#define BK 64        // K tile
#define NTILE (NN/TM)                 // 32
#define NPAIR (NTILE*(NTILE+1)/2)     // 528 blocks: bi <= bj

typedef __bf16 bf16x8 __attribute__((ext_vector_type(8)));
typedef float  f32x4  __attribute__((ext_vector_type(4)));

// async global->LDS, 16B per lane. LDS dest must be wave-uniform base + lane*16.
#define GLOAD_LDS16(gsrc, ldst)                                                  \
    __builtin_amdgcn_global_load_lds(                                            \
        (__attribute__((address_space(1))) void*)(gsrc),                         \
        (__attribute__((address_space(3))) void*)(ldst), 16, 0, 0)

__device__ __forceinline__ unsigned short f2bf(float x) {
    unsigned int u = __float_as_uint(x);
    unsigned int r = (u + 0x7fffu + ((u >> 16) & 1u)) >> 16;  // RNE; inputs finite
    return (unsigned short)r;
}

// ---------------------------------------------------------------------------
// Kernel A: row-normalize z = [z_i; z_j], store bf16 zn[N][D] in workspace.
// One 64-lane wave per row, 4 rows per 256-thread block.
// ---------------------------------------------------------------------------
__global__ __launch_bounds__(256) void normalize_kernel(
        const float* __restrict__ z_i, const float* __restrict__ z_j,
        unsigned short* __restrict__ zn) {
    int row  = blockIdx.x * 4 + (threadIdx.x >> 6);
    int lane = threadIdx.x & 63;
    const float* src = (row < BB) ? (z_i + (size_t)row * DD)
                                  : (z_j + (size_t)(row - BB) * DD);
    const float4* s4 = (const float4*)src;
    float4 v0 = s4[lane * 2 + 0];
    float4 v1 = s4[lane * 2 + 1];
    float ss = v0.x*v0.x + v0.y*v0.y + v0.z*v0.z + v0.w*v0.w
             + v1.x*v1.x + v1.y*v1.y + v1.z*v1.z + v1.w*v1.w;
    #pragma unroll
    for (int off = 1; off < 64; off <<= 1) ss += __shfl_xor(ss, off, 64);
    float inv = 1.0f / fmaxf(sqrtf(ss), 1e-8f);

    float f[8] = {v0.x, v0.y, v0.z, v0.w, v1.x, v1.y, v1.z, v1.w};
    unsigned int p[4];
    #pragma unroll
    for (int k = 0; k < 4; ++k) {
        unsigned int lo = f2bf(f[2*k] * inv);
        unsigned int hi = f2bf(f[2*k+1] * inv);
        p[k] = lo | (hi << 16);
    }
    uint4 out = make_uint4(p[0], p[1], p[2], p[3]);
    *(uint4*)(zn + (size_t)row * DD + lane * 8) = out;
}

// ---------------------------------------------------------------------------
// Kernel B: sim = (zn @ zn^T) * 2. Symmetric: only bi<=bj tiles computed.
// rowsum[r] += sum_j exp(sim[r][j]) via row-sums (bi side) and, for
// off-diagonal tiles, col-sums (bj side, transpose identity).
// 128x128 C-tile / 256-thread block (2x2 waves of 64x64), MFMA 16x16x32 bf16.
// Staging: global_load_lds width=16 (m97); swizzle applied on the GLOBAL
// source side (LDS slot (r,c) holds global chunk c^(r&7)) so the LDS image
// matches the conflict-free XOR layout the compute loop expects.
// ---------------------------------------------------------------------------
__global__ __launch_bounds__(256) void simexp_kernel(
        const unsigned short* __restrict__ zn, float* __restrict__ rowsum) {
    __shared__ __align__(16) unsigned short As[TM * BK];
    __shared__ __align__(16) unsigned short Bs[TM * BK];

    // triangular decode: p -> (bi <= bj)
    int p  = blockIdx.x;
    int bj = (int)((sqrtf(8.0f * (float)p + 1.0f) - 1.0f) * 0.5f);
    while ((bj + 1) * (bj + 2) / 2 <= p) ++bj;
    while (bj * (bj + 1) / 2 > p) --bj;
    int bi = p - bj * (bj + 1) / 2;
    const bool diag = (bi == bj);

    const int tid  = threadIdx.x;
    const int wave = tid >> 6, lane = tid & 63;
    const int wr = wave >> 1, wc = wave & 1;   // 2x2 wave grid, 64x64 each
    const int lrow = lane & 15, quad = lane >> 4;

    f32x4 acc[4][4];
    #pragma unroll
    for (int i = 0; i < 4; ++i)
        #pragma unroll
        for (int j = 0; j < 4; ++j) acc[i][j] = (f32x4){0.f, 0.f, 0.f, 0.f};

    for (int kb = 0; kb < DD; kb += BK) {
        __syncthreads();   // protect LDS from previous iter's readers
        #pragma unroll
        for (int it = 0; it < 4; ++it) {
            int t  = it * 256 + tid;       // chunk-slot 0..1023
            int r  = t >> 3;               // tile row 0..127
            int cc = t & 7;                // LDS chunk slot
            int sc = cc ^ (r & 7);         // global source chunk (swizzle)
            GLOAD_LDS16(zn + (size_t)(bi * TM + r) * DD + kb + sc * 8, As + t * 8);
            GLOAD_LDS16(zn + (size_t)(bj * TM + r) * DD + kb + sc * 8, Bs + t * 8);
        }
        __syncthreads();   // drains vmcnt(0) before LDS reads

        #pragma unroll
        for (int s = 0; s < 2; ++s) {      // two K=32 steps per BK=64
            bf16x8 a[4], b[4];
            #pragma unroll
            for (int ti = 0; ti < 4; ++ti) {
                int m = wr * 64 + ti * 16 + lrow;
                int q = (s * 4 + quad) ^ (m & 7);
                a[ti] = *(const bf16x8*)&As[m * BK + q * 8];
            }
            #pragma unroll
            for (int tj = 0; tj < 4; ++tj) {
                int n = wc * 64 + tj * 16 + lrow;
                int q = (s * 4 + quad) ^ (n & 7);
                b[tj] = *(const bf16x8*)&Bs[n * BK + q * 8];
            }
            #pragma unroll
            for (int ti = 0; ti < 4; ++ti)
                #pragma unroll
                for (int tj = 0; tj < 4; ++tj)
                    acc[ti][tj] = __builtin_amdgcn_mfma_f32_16x16x32_bf16(
                        a[ti], b[tj], acc[ti][tj], 0, 0, 0);
        }
    }

    // Epilogue. C/D layout (verified m89/m91, round-0 absmax 0.0):
    //   tile row r = wr*64 + ti*16 + quad*4 + reg, tile col c = wc*64 + tj*16 + lrow
    float rowpart[4][4];   // [ti][reg] : partial row-sums
    float colpart[4];      // [tj]      : partial col-sums
    #pragma unroll
    for (int i = 0; i < 4; ++i) {
        colpart[i] = 0.f;
        #pragma unroll
        for (int r = 0; r < 4; ++r) rowpart[i][r] = 0.f;
    }
    #pragma unroll
    for (int ti = 0; ti < 4; ++ti)
        #pragma unroll
        for (int tj = 0; tj < 4; ++tj)
            #pragma unroll
            for (int reg = 0; reg < 4; ++reg) {
                float e = __expf(acc[ti][tj][reg] * 2.0f);
                rowpart[ti][reg] += e;
                colpart[tj]      += e;
            }

    // row-sums: reduce over lrow (16-lane groups)
    #pragma unroll
    for (int ti = 0; ti < 4; ++ti) {
        #pragma unroll
        for (int reg = 0; reg < 4; ++reg) {
            float v = rowpart[ti][reg];
            v += __shfl_xor(v, 1, 64);
            v += __shfl_xor(v, 2, 64);
            v += __shfl_xor(v, 4, 64);
            v += __shfl_xor(v, 8, 64);
            if (lrow == 0)
                atomicAdd(&rowsum[bi * TM + wr * 64 + ti * 16 + quad * 4 + reg], v);
        }
    }
    // col-sums -> rows of bj tile (transpose); skip on diagonal tiles
    if (!diag) {
        #pragma unroll
        for (int tj = 0; tj < 4; ++tj) {
            float v = colpart[tj];
            v += __shfl_xor(v, 16, 64);
            v += __shfl_xor(v, 32, 64);
            if (quad == 0)
                atomicAdd(&rowsum[bj * TM + wc * 64 + tj * 16 + lrow], v);
        }
    }
}

// ---------------------------------------------------------------------------
// Kernel C: per-row loss, block-reduced, atomicAdd(loss/N) into out[0].
// loss_row = log(rowsum - exp(sim_ii)) - sim_{i,partner}; dots over the same
// bf16 zn the GEMM consumed so the self-term cancels product-exactly.
// ---------------------------------------------------------------------------
__global__ __launch_bounds__(256) void rowloss_kernel(
        const unsigned short* __restrict__ zn, const float* __restrict__ rowsum,
        float* __restrict__ out) {
    __shared__ float sacc[4];
    int wave = threadIdx.x >> 6, lane = threadIdx.x & 63;
    int row  = blockIdx.x * 4 + wave;
    int partner = (row < BB) ? row + BB : row - BB;

    bf16x8 a = *(const bf16x8*)(zn + (size_t)row * DD + lane * 8);
    bf16x8 q = *(const bf16x8*)(zn + (size_t)partner * DD + lane * 8);
    float self = 0.f, pos = 0.f;
    #pragma unroll
    for (int k = 0; k < 8; ++k) {
        float av = (float)a[k], pv = (float)q[k];
        self += av * av;
        pos  += av * pv;
    }
    #pragma unroll
    for (int off = 1; off < 64; off <<= 1) {
        self += __shfl_xor(self, off, 64);
        pos  += __shfl_xor(pos,  off, 64);
    }
    if (lane == 0)
        sacc[wave] = logf(rowsum[row] - __expf(2.0f * self)) - 2.0f * pos;
    __syncthreads();
    if (threadIdx.x == 0)
        atomicAdd(out, (sacc[0] + sacc[1] + sacc[2] + sacc[3]) * (1.0f / (float)NN));
}

extern "C" void kernel_launch(void* const* d_in, const int* in_sizes, int n_in,
                              void* d_out, int out_size, void* d_ws, size_t ws_size,
                              hipStream_t stream) {
    const float* z_i = (const float*)d_in[0];
    const float* z_j = (const float*)d_in[1];
    float* out = (float*)d_out;

    unsigned short* zn = (unsigned short*)d_ws;                    // N*D bf16 = 4 MB
    float* rowsum = (float*)((char*)d_ws + (size_t)NN * DD * 2);   // N floats

    hipMemsetAsync(out, 0, sizeof(float), stream);
    hipMemsetAsync(rowsum, 0, NN * sizeof(float), stream);
    normalize_kernel<<<NN / 4, 256, 0, stream>>>(z_i, z_j, zn);
    simexp_kernel<<<NPAIR, 256, 0, stream>>>(zn, rowsum);
    rowloss_kernel<<<NN / 4, 256, 0, stream>>>(zn, rowsum, out);
}

// Round 3
// 87.221 us; speedup vs baseline: 1.2358x; 1.2222x over previous
//
#include <hip/hip_runtime.h>
#include <hip/hip_bf16.h>

#define NN 4096      // N = 2*B
#define BB 2048      // B
#define DD 512       // D
#define TM 128       // C tile (M and N)
#define BK 64        // K tile
#define NTILE (NN/TM)                 // 32
#define NPAIR (NTILE*(NTILE+1)/2)     // 528 blocks: bi <= bj

typedef __bf16 bf16x8 __attribute__((ext_vector_type(8)));
typedef float  f32x4  __attribute__((ext_vector_type(4)));

// async global->LDS, 16B per lane. LDS dest must be wave-uniform base + lane*16.
#define GLOAD_LDS16(gsrc, ldst)                                                  \
    __builtin_amdgcn_global_load_lds(                                            \
        (__attribute__((address_space(1))) void*)(gsrc),                         \
        (__attribute__((address_space(3))) void*)(ldst), 16, 0, 0)

__device__ __forceinline__ unsigned short f2bf(float x) {
    unsigned int u = __float_as_uint(x);
    unsigned int r = (u + 0x7fffu + ((u >> 16) & 1u)) >> 16;  // RNE; inputs finite
    return (unsigned short)r;
}

// ---------------------------------------------------------------------------
// Kernel A: row-normalize z = [z_i; z_j] -> bf16 zn[N][D]; also zero-inits
// rowsum[] and out[0] (stream order makes these visible to later kernels),
// eliminating both hipMemsetAsync dispatches.
// ---------------------------------------------------------------------------
__global__ __launch_bounds__(256) void normalize_kernel(
        const float* __restrict__ z_i, const float* __restrict__ z_j,
        unsigned short* __restrict__ zn, float* __restrict__ rowsum,
        float* __restrict__ out) {
    if (threadIdx.x < 4) rowsum[blockIdx.x * 4 + threadIdx.x] = 0.f;
    if (blockIdx.x == 0 && threadIdx.x == 0) out[0] = 0.f;

    int row  = blockIdx.x * 4 + (threadIdx.x >> 6);
    int lane = threadIdx.x & 63;
    const float* src = (row < BB) ? (z_i + (size_t)row * DD)
                                  : (z_j + (size_t)(row - BB) * DD);
    const float4* s4 = (const float4*)src;
    float4 v0 = s4[lane * 2 + 0];
    float4 v1 = s4[lane * 2 + 1];
    float ss = v0.x*v0.x + v0.y*v0.y + v0.z*v0.z + v0.w*v0.w
             + v1.x*v1.x + v1.y*v1.y + v1.z*v1.z + v1.w*v1.w;
    #pragma unroll
    for (int off = 1; off < 64; off <<= 1) ss += __shfl_xor(ss, off, 64);
    float inv = 1.0f / fmaxf(sqrtf(ss), 1e-8f);

    float f[8] = {v0.x, v0.y, v0.z, v0.w, v1.x, v1.y, v1.z, v1.w};
    unsigned int p[4];
    #pragma unroll
    for (int k = 0; k < 4; ++k) {
        unsigned int lo = f2bf(f[2*k] * inv);
        unsigned int hi = f2bf(f[2*k+1] * inv);
        p[k] = lo | (hi << 16);
    }
    uint4 outv = make_uint4(p[0], p[1], p[2], p[3]);
    *(uint4*)(zn + (size_t)row * DD + lane * 8) = outv;
}

// ---------------------------------------------------------------------------
// Kernel B: sim = (zn @ zn^T) * 2, upper-triangular tiles only (bi <= bj).
// rowsum[r] += sum_j exp(sim[r][j]) via row-sums + (off-diag) col-sums.
// Additionally extracts the matrix entries the loss needs:
//   diag tiles (bi==bj):  selfsim[r] = sim[r][r]
//   pos tiles (bj==bi+16): possim[r] = possim[r+B] = sim[r][r+B]
// so the final kernel never re-reads zn.
// 128x128 C-tile / 256 threads (2x2 waves of 64x64), MFMA 16x16x32 bf16,
// global_load_lds width=16 staging with source-side XOR swizzle.
// ---------------------------------------------------------------------------
__global__ __launch_bounds__(256) void simexp_kernel(
        const unsigned short* __restrict__ zn, float* __restrict__ rowsum,
        float* __restrict__ selfsim, float* __restrict__ possim) {
    __shared__ __align__(16) unsigned short As[TM * BK];
    __shared__ __align__(16) unsigned short Bs[TM * BK];

    // triangular decode: p -> (bi <= bj)
    int p  = blockIdx.x;
    int bj = (int)((sqrtf(8.0f * (float)p + 1.0f) - 1.0f) * 0.5f);
    while ((bj + 1) * (bj + 2) / 2 <= p) ++bj;
    while (bj * (bj + 1) / 2 > p) --bj;
    int bi = p - bj * (bj + 1) / 2;
    const bool diag = (bi == bj);

    const int tid  = threadIdx.x;
    const int wave = tid >> 6, lane = tid & 63;
    const int wr = wave >> 1, wc = wave & 1;   // 2x2 wave grid, 64x64 each
    const int lrow = lane & 15, quad = lane >> 4;

    f32x4 acc[4][4];
    #pragma unroll
    for (int i = 0; i < 4; ++i)
        #pragma unroll
        for (int j = 0; j < 4; ++j) acc[i][j] = (f32x4){0.f, 0.f, 0.f, 0.f};

    const unsigned short* Bsrc = diag ? As : Bs;   // diag tiles reuse As

    for (int kb = 0; kb < DD; kb += BK) {
        __syncthreads();   // protect LDS from previous iter's readers
        #pragma unroll
        for (int it = 0; it < 4; ++it) {
            int t  = it * 256 + tid;       // chunk-slot 0..1023
            int r  = t >> 3;               // tile row 0..127
            int cc = t & 7;                // LDS chunk slot
            int sc = cc ^ (r & 7);         // global source chunk (swizzle)
            GLOAD_LDS16(zn + (size_t)(bi * TM + r) * DD + kb + sc * 8, As + t * 8);
            if (!diag)
                GLOAD_LDS16(zn + (size_t)(bj * TM + r) * DD + kb + sc * 8, Bs + t * 8);
        }
        __syncthreads();   // drains vmcnt(0) before LDS reads

        #pragma unroll
        for (int s = 0; s < 2; ++s) {      // two K=32 steps per BK=64
            bf16x8 a[4], b[4];
            #pragma unroll
            for (int ti = 0; ti < 4; ++ti) {
                int m = wr * 64 + ti * 16 + lrow;
                int q = (s * 4 + quad) ^ (m & 7);
                a[ti] = *(const bf16x8*)&As[m * BK + q * 8];
            }
            #pragma unroll
            for (int tj = 0; tj < 4; ++tj) {
                int n = wc * 64 + tj * 16 + lrow;
                int q = (s * 4 + quad) ^ (n & 7);
                b[tj] = *(const bf16x8*)&Bsrc[n * BK + q * 8];
            }
            #pragma unroll
            for (int ti = 0; ti < 4; ++ti)
                #pragma unroll
                for (int tj = 0; tj < 4; ++tj)
                    acc[ti][tj] = __builtin_amdgcn_mfma_f32_16x16x32_bf16(
                        a[ti], b[tj], acc[ti][tj], 0, 0, 0);
        }
    }

    // Epilogue. C/D layout (verified, absmax 0.0 in R0/R1):
    //   tile row = wr*64 + ti*16 + quad*4 + reg, tile col = wc*64 + tj*16 + lrow
    float rowpart[4][4];   // [ti][reg]
    float colpart[4];      // [tj]
    #pragma unroll
    for (int i = 0; i < 4; ++i) {
        colpart[i] = 0.f;
        #pragma unroll
        for (int r = 0; r < 4; ++r) rowpart[i][r] = 0.f;
    }
    #pragma unroll
    for (int ti = 0; ti < 4; ++ti)
        #pragma unroll
        for (int tj = 0; tj < 4; ++tj)
            #pragma unroll
            for (int reg = 0; reg < 4; ++reg) {
                float e = __expf(acc[ti][tj][reg] * 2.0f);
                rowpart[ti][reg] += e;
                colpart[tj]      += e;
            }

    // row-sums: reduce over lrow (16-lane groups)
    #pragma unroll
    for (int ti = 0; ti < 4; ++ti) {
        #pragma unroll
        for (int reg = 0; reg < 4; ++reg) {
            float v = rowpart[ti][reg];
            v += __shfl_xor(v, 1, 64);
            v += __shfl_xor(v, 2, 64);
            v += __shfl_xor(v, 4, 64);
            v += __shfl_xor(v, 8, 64);
            if (lrow == 0)
                atomicAdd(&rowsum[bi * TM + wr * 64 + ti * 16 + quad * 4 + reg], v);
        }
    }
    // col-sums -> rows of bj tile (transpose); skip on diagonal tiles
    if (!diag) {
        #pragma unroll
        for (int tj = 0; tj < 4; ++tj) {
            float v = colpart[tj];
            v += __shfl_xor(v, 16, 64);
            v += __shfl_xor(v, 32, 64);
            if (quad == 0)
                atomicAdd(&rowsum[bj * TM + wc * 64 + tj * 16 + lrow], v);
        }
    }

    // tile-diagonal extraction: lanes lrow>>2==quad in waves wr==wc hold
    // element (r, r) of the tile at acc[ti][ti][lrow&3], r = wr*64+ti*16+lrow.
    const bool posb = (bj == bi + NTILE / 2);   // bj == bi + 16  (col offset B)
    if ((diag || posb) && wr == wc && (lrow >> 2) == quad) {
        #pragma unroll
        for (int ti = 0; ti < 4; ++ti) {
            float v = 2.0f * acc[ti][ti][lrow & 3];
            int R = bi * TM + wr * 64 + ti * 16 + lrow;
            if (diag) {
                selfsim[R] = v;
            } else {
                possim[R]      = v;   // sim[r][r+B]
                possim[R + BB] = v;   // == sim[r+B][r]
            }
        }
    }
}

// ---------------------------------------------------------------------------
// Kernel C: loss_r = log(rowsum_r - exp(selfsim_r)) - possim_r; block-reduce;
// atomicAdd(out, sum/N). 3 float reads per row — no zn traffic.
// ---------------------------------------------------------------------------
__global__ __launch_bounds__(256) void rowfinal_kernel(
        const float* __restrict__ rowsum, const float* __restrict__ selfsim,
        const float* __restrict__ possim, float* __restrict__ out) {
    __shared__ float s[256];
    int r = blockIdx.x * 256 + threadIdx.x;
    s[threadIdx.x] = logf(rowsum[r] - __expf(selfsim[r])) - possim[r];
    __syncthreads();
    #pragma unroll
    for (int off = 128; off > 0; off >>= 1) {
        if (threadIdx.x < off) s[threadIdx.x] += s[threadIdx.x + off];
        __syncthreads();
    }
    if (threadIdx.x == 0) atomicAdd(out, s[0] * (1.0f / (float)NN));
}

extern "C" void kernel_launch(void* const* d_in, const int* in_sizes, int n_in,
                              void* d_out, int out_size, void* d_ws, size_t ws_size,
                              hipStream_t stream) {
    const float* z_i = (const float*)d_in[0];
    const float* z_j = (const float*)d_in[1];
    float* out = (float*)d_out;

    unsigned short* zn = (unsigned short*)d_ws;                    // N*D bf16 = 4 MB
    float* rowsum  = (float*)((char*)d_ws + (size_t)NN * DD * 2);  // N floats
    float* selfsim = rowsum + NN;                                  // N floats
    float* possim  = selfsim + NN;                                 // N floats

    normalize_kernel<<<NN / 4, 256, 0, stream>>>(z_i, z_j, zn, rowsum, out);
    simexp_kernel<<<NPAIR, 256, 0, stream>>>(zn, rowsum, selfsim, possim);
    rowfinal_kernel<<<NN / 256, 256, 0, stream>>>(rowsum, selfsim, possim, out);
}